// Round 11
// baseline (73.468 us; speedup 1.0000x reference)
//
#include <hip/hip_runtime.h>
#include <math.h>

#define MAXF   32
#define FTOUT  512
#define VFT    768
#define FTIN   49152
#define NCHUNK 8
#define RPB    32              // batch rows per block (4 waves x 8 rows)

// ---------------------------------------------------------------------------
// Kernel 1: per-feature-row quantize: Wq[f][j] = u8( rint((W_ft+W_fft)/scale_f) + 128 )
// scale_f = rowmax|w| / 127. One wave per feature row.
// ---------------------------------------------------------------------------
__global__ __launch_bounds__(256)
void build_q8(const float* __restrict__ W_ft,
              const float* __restrict__ W_fft,
              unsigned char* __restrict__ Wq,
              float* __restrict__ scale)
{
    const int f    = blockIdx.x * 4 + (threadIdx.x >> 6);
    const int lane = threadIdx.x & 63;
    const long long rb = (long long)f * FTOUT + lane * 8;
    const float4 a0 = *(const float4*)(W_ft + rb);
    const float4 a1 = *(const float4*)(W_ft + rb + 4);
    const int fv = f % VFT;
    const float4 c0 = *(const float4*)(W_fft + fv * FTOUT + lane * 8);
    const float4 c1 = *(const float4*)(W_fft + fv * FTOUT + lane * 8 + 4);
    float w[8] = {a0.x+c0.x, a0.y+c0.y, a0.z+c0.z, a0.w+c0.w,
                  a1.x+c1.x, a1.y+c1.y, a1.z+c1.z, a1.w+c1.w};
    float m = fabsf(w[0]);
    #pragma unroll
    for (int t = 1; t < 8; ++t) m = fmaxf(m, fabsf(w[t]));
    #pragma unroll
    for (int s = 1; s < 64; s <<= 1) m = fmaxf(m, __shfl_xor(m, s));
    const float inv = (m > 0.f) ? 127.f / m : 0.f;
    if (lane == 0) scale[f] = (m > 0.f) ? m * (1.f / 127.f) : 0.f;
    unsigned u[8];
    #pragma unroll
    for (int t = 0; t < 8; ++t)
        u[t] = (unsigned)((int)rintf(w[t] * inv) + 128);
    uint2 o;
    o.x = u[0] | (u[1] << 8) | (u[2] << 16) | (u[3] << 24);
    o.y = u[4] | (u[5] << 8) | (u[6] << 16) | (u[7] << 24);
    *(uint2*)(Wq + (long long)f * FTOUT + lane * 8) = o;
}

// ---------------------------------------------------------------------------
// Kernel 1b: pack per-row feature ids (u16) and pre-scaled values v*scale[f].
// ---------------------------------------------------------------------------
__global__ __launch_bounds__(256)
void prep_idx(const int* __restrict__ stm_idx,
              const int* __restrict__ nstm_idx,
              const float* __restrict__ values,
              const float* __restrict__ scale,
              unsigned short* __restrict__ off16,
              float* __restrict__ val_s,
              float* __restrict__ val_n,
              int nnz, int batch)
{
    const int t = blockIdx.x * 256 + threadIdx.x;
    if (t >= batch * 64) return;
    const int b = t >> 6;
    const int k = t & 63;
    const int g = b * MAXF + (k & 31);
    const int f = (k < 32 ? stm_idx : nstm_idx)[nnz + g];
    off16[t] = (unsigned short)f;
    const float vs = values[g] * scale[f];
    if (k < 32) val_s[b * 32 + k] = vs;
    else        val_n[b * 32 + (k - 32)] = vs;
}

// biased-u8 consume: A[t] += V * byte_t(W)   (bias handled via corr)
#define CONS_U8(A, W, V) do {                                     \
    A[0] = fmaf(V, (float)((W).x & 0xffu),         A[0]);         \
    A[1] = fmaf(V, (float)(((W).x >> 8)  & 0xffu), A[1]);         \
    A[2] = fmaf(V, (float)(((W).x >> 16) & 0xffu), A[2]);         \
    A[3] = fmaf(V, (float)((W).x >> 24),           A[3]);         \
    A[4] = fmaf(V, (float)((W).y & 0xffu),         A[4]);         \
    A[5] = fmaf(V, (float)(((W).y >> 8)  & 0xffu), A[5]);         \
    A[6] = fmaf(V, (float)(((W).y >> 16) & 0xffu), A[6]);         \
    A[7] = fmaf(V, (float)((W).y >> 24),           A[7]);         \
} while (0)

// ---------------------------------------------------------------------------
// Kernel 2: chunked int8 gather, butterfly-free.
// lane = (ri:3)(cg:3): each lane owns (row ri, col-octet cg) completely and
// accumulates all 32 stm + 32 nstm features itself. No cross-lane reduction
// until the final 3-stage cg sum. Offsets read as packed u16 pairs, values
// as float2 -> 2 DS reads per 2 features. Chunk c -> XCD c.
// ---------------------------------------------------------------------------
__global__ __launch_bounds__(256, 6)
void gather_q8(const unsigned char* __restrict__ Wq,
               const unsigned short* __restrict__ off16,
               const float* __restrict__ val_s,
               const float* __restrict__ val_n,
               const float* __restrict__ b_ft,
               const float* __restrict__ b_fft,
               const float* __restrict__ W_out,
               float* __restrict__ partial,
               int batch)
{
    const int c    = blockIdx.x & (NCHUNK - 1);   // chunk -> XCD
    const int rg   = blockIdx.x >> 3;
    const int tid  = threadIdx.x;
    const int wid  = tid >> 6;
    const int lane = tid & 63;
    const int ri   = lane >> 3;        // row within wave's 8
    const int cg   = lane & 7;         // col octet

    __shared__ unsigned s_offp[RPB][33];   // 32 packed u16-pairs + pad
    __shared__ float    s_val[RPB][66];    // 64 values (32 stm + 32 nstm) + pad

    const int row_base = rg * RPB;

    // stage offsets: 32 rows x 32 u32 (packed u16 pairs), coalesced
    {
        const unsigned* src = (const unsigned*)(off16 + row_base * 64); // 1024 u32
        #pragma unroll
        for (int i = 0; i < 4; ++i) {
            const int idx = i * 256 + tid;
            s_offp[idx >> 5][idx & 31] = src[idx];
        }
        // stage values: 32 rows x 64 floats
        #pragma unroll
        for (int i = 0; i < 8; ++i) {
            const int idx = i * 256 + tid;     // 2048
            const int row = idx >> 6;
            const int k   = idx & 63;
            s_val[row][k] = (k < 32) ? val_s[(row_base + row) * 32 + k]
                                     : val_n[(row_base + row) * 32 + (k - 32)];
        }
    }
    __syncthreads();

    // per-lane constants: 8 cols at col = c*64 + cg*8
    const int col = c * 64 + cg * 8;
    float bb[8], wos[8], won[8];
    {
        const float4 a0 = *(const float4*)(b_ft + col);
        const float4 a1 = *(const float4*)(b_ft + col + 4);
        const float4 f0 = *(const float4*)(b_fft + col);
        const float4 f1 = *(const float4*)(b_fft + col + 4);
        bb[0]=a0.x+f0.x; bb[1]=a0.y+f0.y; bb[2]=a0.z+f0.z; bb[3]=a0.w+f0.w;
        bb[4]=a1.x+f1.x; bb[5]=a1.y+f1.y; bb[6]=a1.z+f1.z; bb[7]=a1.w+f1.w;
        const float4 s0 = *(const float4*)(W_out + col);
        const float4 s1 = *(const float4*)(W_out + col + 4);
        const float4 n0 = *(const float4*)(W_out + FTOUT + col);
        const float4 n1 = *(const float4*)(W_out + FTOUT + col + 4);
        wos[0]=s0.x; wos[1]=s0.y; wos[2]=s0.z; wos[3]=s0.w;
        wos[4]=s1.x; wos[5]=s1.y; wos[6]=s1.z; wos[7]=s1.w;
        won[0]=n0.x; won[1]=n0.y; won[2]=n0.z; won[3]=n0.w;
        won[4]=n1.x; won[5]=n1.y; won[6]=n1.z; won[7]=n1.w;
    }

    const char* wb = (const char*)Wq;
    const unsigned colb = (unsigned)(c * 64 + cg * 8);  // byte offset in 512B row

    const int row_l = wid * 8 + ri;
    const int row_g = row_base + row_l;

    float acc_s[8] = {0.f,0.f,0.f,0.f,0.f,0.f,0.f,0.f};
    float acc_n[8] = {0.f,0.f,0.f,0.f,0.f,0.f,0.f,0.f};
    float corr_s = 0.f, corr_n = 0.f;

    // stm: 16 packed pairs = 32 features
    #pragma unroll 4
    for (int kk = 0; kk < 16; ++kk) {
        const unsigned p = s_offp[row_l][kk];
        const float2 v = *(const float2*)&s_val[row_l][2 * kk];
        const uint2 w0 = *(const uint2*)(wb + ((p & 0xffffu) << 9) + colb);
        const uint2 w1 = *(const uint2*)(wb + ((p >> 16) << 9) + colb);
        corr_s += v.x + v.y;
        CONS_U8(acc_s, w0, v.x);
        CONS_U8(acc_s, w1, v.y);
    }
    // nstm: pairs 16..31
    #pragma unroll 4
    for (int kk = 16; kk < 32; ++kk) {
        const unsigned p = s_offp[row_l][kk];
        const float2 v = *(const float2*)&s_val[row_l][2 * kk];
        const uint2 w0 = *(const uint2*)(wb + ((p & 0xffffu) << 9) + colb);
        const uint2 w1 = *(const uint2*)(wb + ((p >> 16) << 9) + colb);
        corr_n += v.x + v.y;
        CONS_U8(acc_n, w0, v.x);
        CONS_U8(acc_n, w1, v.y);
    }

    const float cs = 128.f * corr_s;
    const float cn = 128.f * corr_n;

    float part = 0.f;
    #pragma unroll
    for (int t = 0; t < 8; ++t) {
        const float hs = fminf(fmaxf(acc_s[t] - cs + bb[t], 0.f), 1.f);
        part = fmaf(hs, wos[t], part);
    }
    #pragma unroll
    for (int t = 0; t < 8; ++t) {
        const float hn = fminf(fmaxf(acc_n[t] - cn + bb[t], 0.f), 1.f);
        part = fmaf(hn, won[t], part);
    }
    // cg sum (lane bits 0..2); rows live in bits 3..5, untouched
    part += __shfl_xor(part, 1);
    part += __shfl_xor(part, 2);
    part += __shfl_xor(part, 4);

    if (cg == 0 && row_g < batch)
        partial[row_g * NCHUNK + c] = part;
}

// ---------------------------------------------------------------------------
// Kernel 3: combine 8 chunk partials -> sigmoid
// ---------------------------------------------------------------------------
__global__ __launch_bounds__(256)
void final_out(const float* __restrict__ partial,
               const float* __restrict__ b_out,
               float* __restrict__ out, int batch)
{
    const int b = blockIdx.x * 256 + threadIdx.x;
    if (b >= batch) return;
    const float4 p0 = *(const float4*)(partial + b * NCHUNK);
    const float4 p1 = *(const float4*)(partial + b * NCHUNK + 4);
    const float tot = ((p0.x + p0.y) + (p0.z + p0.w))
                    + ((p1.x + p1.y) + (p1.z + p1.w)) + b_out[0];
    out[b] = 1.0f / (1.0f + expf(-tot));
}

// ---------------------------------------------------------------------------
// Fallback: no workspace needed (round-1 kernel).
// ---------------------------------------------------------------------------
__global__ __launch_bounds__(256)
void nnhalfka_fused(const int* __restrict__ stm_idx,
                    const int* __restrict__ nstm_idx,
                    const float* __restrict__ values,
                    const float* __restrict__ W_ft,
                    const float* __restrict__ b_ft,
                    const float* __restrict__ W_fft,
                    const float* __restrict__ b_fft,
                    const float* __restrict__ W_out,
                    const float* __restrict__ b_out,
                    float* __restrict__ out,
                    int nnz)
{
    const int b   = blockIdx.x;
    const int tid = threadIdx.x;

    __shared__ int   s_fs[MAXF], s_fsm[MAXF], s_fn[MAXF], s_fnm[MAXF];
    __shared__ float s_v[MAXF];
    __shared__ float s_red[4];

    if (tid < MAXF) {
        const int g  = b * MAXF + tid;
        const int fs = stm_idx[nnz + g];
        const int fn = nstm_idx[nnz + g];
        s_fs[tid]  = fs * FTOUT;
        s_fsm[tid] = (fs % VFT) * FTOUT;
        s_fn[tid]  = fn * FTOUT;
        s_fnm[tid] = (fn % VFT) * FTOUT;
        s_v[tid]   = values[g];
    }
    __syncthreads();

    const int j = tid * 2;
    float2 accs = make_float2(0.f, 0.f);
    float2 accn = make_float2(0.f, 0.f);

    #pragma unroll 4
    for (int k = 0; k < MAXF; ++k) {
        const float v    = s_v[k];
        const float2 ws  = *(const float2*)(W_ft  + s_fs[k]  + j);
        const float2 wfs = *(const float2*)(W_fft + s_fsm[k] + j);
        const float2 wn  = *(const float2*)(W_ft  + s_fn[k]  + j);
        const float2 wfn = *(const float2*)(W_fft + s_fnm[k] + j);
        accs.x += v * (ws.x + wfs.x);
        accs.y += v * (ws.y + wfs.y);
        accn.x += v * (wn.x + wfn.x);
        accn.y += v * (wn.y + wfn.y);
    }

    const float bb0 = b_ft[j]     + b_fft[j];
    const float bb1 = b_ft[j + 1] + b_fft[j + 1];
    const float hs0 = fminf(fmaxf(accs.x + bb0, 0.f), 1.f);
    const float hs1 = fminf(fmaxf(accs.y + bb1, 0.f), 1.f);
    const float hn0 = fminf(fmaxf(accn.x + bb0, 0.f), 1.f);
    const float hn1 = fminf(fmaxf(accn.y + bb1, 0.f), 1.f);

    float partial = hs0 * W_out[j]         + hs1 * W_out[j + 1]
                  + hn0 * W_out[FTOUT + j] + hn1 * W_out[FTOUT + j + 1];
    #pragma unroll
    for (int off = 32; off > 0; off >>= 1)
        partial += __shfl_down(partial, off);
    if ((tid & 63) == 0) s_red[tid >> 6] = partial;
    __syncthreads();
    if (tid == 0) {
        const float tot = s_red[0] + s_red[1] + s_red[2] + s_red[3] + b_out[0];
        out[b] = 1.0f / (1.0f + expf(-tot));
    }
}

extern "C" void kernel_launch(void* const* d_in, const int* in_sizes, int n_in,
                              void* d_out, int out_size, void* d_ws, size_t ws_size,
                              hipStream_t stream) {
    const int*   stm_idx  = (const int*)d_in[0];
    const int*   nstm_idx = (const int*)d_in[1];
    const float* values   = (const float*)d_in[2];
    const float* W_ft     = (const float*)d_in[4];
    const float* b_ft     = (const float*)d_in[5];
    const float* W_fft    = (const float*)d_in[6];
    const float* b_fft    = (const float*)d_in[7];
    const float* W_out    = (const float*)d_in[8];
    const float* b_out    = (const float*)d_in[9];
    float* out = (float*)d_out;

    const int nnz   = in_sizes[0] / 2;
    const int batch = out_size;

    const size_t WQ_B   = (size_t)FTIN * FTOUT;          // 25,165,824
    const size_t SC_B   = (size_t)FTIN * 4;              // 196,608
    const size_t OFF_B  = (size_t)batch * 64 * 2;
    const size_t VS_B   = (size_t)batch * 32 * 4;
    const size_t VN_B   = (size_t)batch * 32 * 4;
    const size_t PART_B = (size_t)batch * NCHUNK * 4;
    const size_t need = WQ_B + SC_B + OFF_B + VS_B + VN_B + PART_B;

    if (ws_size >= need && (batch % RPB) == 0) {
        char* p = (char*)d_ws;
        unsigned char*  Wq      = (unsigned char*)p;        p += WQ_B;
        float*          scale   = (float*)p;                p += SC_B;
        unsigned short* off16   = (unsigned short*)p;       p += OFF_B;
        float*          val_s   = (float*)p;                p += VS_B;
        float*          val_n   = (float*)p;                p += VN_B;
        float*          partial = (float*)p;

        build_q8<<<FTIN / 4, 256, 0, stream>>>(W_ft, W_fft, Wq, scale);
        prep_idx<<<(batch * 64 + 255) / 256, 256, 0, stream>>>(
            stm_idx, nstm_idx, values, scale, off16, val_s, val_n, nnz, batch);
        gather_q8<<<(batch / RPB) * NCHUNK, 256, 0, stream>>>(
            Wq, off16, val_s, val_n, b_ft, b_fft, W_out, partial, batch);
        final_out<<<(batch + 255) / 256, 256, 0, stream>>>(partial, b_out, out, batch);
    } else {
        nnhalfka_fused<<<batch, 256, 0, stream>>>(
            stm_idx, nstm_idx, values, W_ft, b_ft, W_fft, b_fft, W_out, b_out,
            out, nnz);
    }
}

// Round 12
// 68.627 us; speedup vs baseline: 1.0705x; 1.0705x over previous
//
#include <hip/hip_runtime.h>
#include <math.h>

#define MAXF   32
#define FTOUT  512
#define VFT    768
#define FTIN   49152
#define NCHUNK 8
#define RPB    32              // batch rows per block (4 waves x 4 iters x 2 rows)

// ---------------------------------------------------------------------------
// Kernel 1: per-feature-row quantize: Wq[f][j] = u8( rint((W_ft+W_fft)/scale_f) + 128 )
// scale_f = rowmax|w| / 127. One wave per feature row.
// ~19 us = compulsory 96 MB W_ft read + 24 MB write at HBM floor.
// ---------------------------------------------------------------------------
__global__ __launch_bounds__(256)
void build_q8(const float* __restrict__ W_ft,
              const float* __restrict__ W_fft,
              unsigned char* __restrict__ Wq,
              float* __restrict__ scale)
{
    const int f    = blockIdx.x * 4 + (threadIdx.x >> 6);
    const int lane = threadIdx.x & 63;
    const long long rb = (long long)f * FTOUT + lane * 8;
    const float4 a0 = *(const float4*)(W_ft + rb);
    const float4 a1 = *(const float4*)(W_ft + rb + 4);
    const int fv = f % VFT;
    const float4 c0 = *(const float4*)(W_fft + fv * FTOUT + lane * 8);
    const float4 c1 = *(const float4*)(W_fft + fv * FTOUT + lane * 8 + 4);
    float w[8] = {a0.x+c0.x, a0.y+c0.y, a0.z+c0.z, a0.w+c0.w,
                  a1.x+c1.x, a1.y+c1.y, a1.z+c1.z, a1.w+c1.w};
    float m = fabsf(w[0]);
    #pragma unroll
    for (int t = 1; t < 8; ++t) m = fmaxf(m, fabsf(w[t]));
    #pragma unroll
    for (int s = 1; s < 64; s <<= 1) m = fmaxf(m, __shfl_xor(m, s));
    const float inv = (m > 0.f) ? 127.f / m : 0.f;
    if (lane == 0) scale[f] = (m > 0.f) ? m * (1.f / 127.f) : 0.f;
    unsigned u[8];
    #pragma unroll
    for (int t = 0; t < 8; ++t)
        u[t] = (unsigned)((int)rintf(w[t] * inv) + 128);
    uint2 o;
    o.x = u[0] | (u[1] << 8) | (u[2] << 16) | (u[3] << 24);
    o.y = u[4] | (u[5] << 8) | (u[6] << 16) | (u[7] << 24);
    *(uint2*)(Wq + (long long)f * FTOUT + lane * 8) = o;
}

// ---------------------------------------------------------------------------
// Kernel 1b: pack per-row feature ids (u16) and pre-scaled values v*scale[f].
// ---------------------------------------------------------------------------
__global__ __launch_bounds__(256)
void prep_idx(const int* __restrict__ stm_idx,
              const int* __restrict__ nstm_idx,
              const float* __restrict__ values,
              const float* __restrict__ scale,
              unsigned short* __restrict__ off16,
              float* __restrict__ val_s,
              float* __restrict__ val_n,
              int nnz, int batch)
{
    const int t = blockIdx.x * 256 + threadIdx.x;
    if (t >= batch * 64) return;
    const int b = t >> 6;
    const int k = t & 63;
    const int g = b * MAXF + (k & 31);
    const int f = (k < 32 ? stm_idx : nstm_idx)[nnz + g];
    off16[t] = (unsigned short)f;
    const float vs = values[g] * scale[f];
    if (k < 32) val_s[b * 32 + k] = vs;
    else        val_n[b * 32 + (k - 32)] = vs;
}

// biased-u8 consume: A[t] += V * byte_t(W)   (bias handled via corr)
#define CONS_U8(A, W, V) do {                                     \
    A[0] = fmaf(V, (float)((W).x & 0xffu),         A[0]);         \
    A[1] = fmaf(V, (float)(((W).x >> 8)  & 0xffu), A[1]);         \
    A[2] = fmaf(V, (float)(((W).x >> 16) & 0xffu), A[2]);         \
    A[3] = fmaf(V, (float)((W).x >> 24),           A[3]);         \
    A[4] = fmaf(V, (float)((W).y & 0xffu),         A[4]);         \
    A[5] = fmaf(V, (float)(((W).y >> 8)  & 0xffu), A[5]);         \
    A[6] = fmaf(V, (float)(((W).y >> 16) & 0xffu), A[6]);         \
    A[7] = fmaf(V, (float)((W).y >> 24),           A[7]);         \
} while (0)

// ---------------------------------------------------------------------------
// Kernel 2 (R9-proven): chunked int8 gather, 2 rows per wave-iteration.
// lane = (r:1)(fg:2)(cg:3). Per iter: 16 uint2 gathers (8 stm + 8 nstm),
// each instr = 8 features x 64 B chunk segment. Chunk c pinned to XCD c.
// ---------------------------------------------------------------------------
__global__ __launch_bounds__(256, 4)
void gather_q8(const unsigned char* __restrict__ Wq,
               const unsigned short* __restrict__ off16,
               const float* __restrict__ val_s,
               const float* __restrict__ val_n,
               const float* __restrict__ b_ft,
               const float* __restrict__ b_fft,
               const float* __restrict__ W_out,
               float* __restrict__ partial,
               int batch)
{
    const int c    = blockIdx.x & (NCHUNK - 1);   // chunk -> XCD
    const int rg   = blockIdx.x >> 3;
    const int tid  = threadIdx.x;
    const int wid  = tid >> 6;
    const int lane = tid & 63;
    const int r    = lane >> 5;
    const int fg   = (lane >> 3) & 3;
    const int cg   = lane & 7;

    __shared__ int   s_off[RPB][64];    // byte offsets f*512
    __shared__ float s_vs[RPB][32];
    __shared__ float s_vn[RPB][32];

    const int row_base = rg * RPB;

    // stage offsets + values (coalesced). 2048 u16 -> 4 u32 per thread.
    {
        const unsigned* src = (const unsigned*)(off16 + row_base * 64); // 1024 u32
        const unsigned p0 = src[tid * 4 + 0];
        const unsigned p1 = src[tid * 4 + 1];
        const unsigned p2 = src[tid * 4 + 2];
        const unsigned p3 = src[tid * 4 + 3];
        int* so = (int*)s_off;
        so[tid * 8 + 0] = (int)(p0 & 0xffffu) << 9;
        so[tid * 8 + 1] = (int)(p0 >> 16)     << 9;
        so[tid * 8 + 2] = (int)(p1 & 0xffffu) << 9;
        so[tid * 8 + 3] = (int)(p1 >> 16)     << 9;
        so[tid * 8 + 4] = (int)(p2 & 0xffffu) << 9;
        so[tid * 8 + 5] = (int)(p2 >> 16)     << 9;
        so[tid * 8 + 6] = (int)(p3 & 0xffffu) << 9;
        so[tid * 8 + 7] = (int)(p3 >> 16)     << 9;
        ((float4*)s_vs)[tid] = ((const float4*)(val_s + row_base * 32))[tid];
        ((float4*)s_vn)[tid] = ((const float4*)(val_n + row_base * 32))[tid];
    }
    __syncthreads();

    // per-lane constants: 8 cols at col = c*64 + cg*8
    const int col = c * 64 + cg * 8;
    float bbq[8], wos[8], won[8];
    {
        const float4 a0 = *(const float4*)(b_ft + col);
        const float4 a1 = *(const float4*)(b_ft + col + 4);
        const float4 f0 = *(const float4*)(b_fft + col);
        const float4 f1 = *(const float4*)(b_fft + col + 4);
        bbq[0]=(a0.x+f0.x)*0.25f; bbq[1]=(a0.y+f0.y)*0.25f;
        bbq[2]=(a0.z+f0.z)*0.25f; bbq[3]=(a0.w+f0.w)*0.25f;
        bbq[4]=(a1.x+f1.x)*0.25f; bbq[5]=(a1.y+f1.y)*0.25f;
        bbq[6]=(a1.z+f1.z)*0.25f; bbq[7]=(a1.w+f1.w)*0.25f;
        const float4 s0 = *(const float4*)(W_out + col);
        const float4 s1 = *(const float4*)(W_out + col + 4);
        const float4 n0 = *(const float4*)(W_out + FTOUT + col);
        const float4 n1 = *(const float4*)(W_out + FTOUT + col + 4);
        wos[0]=s0.x; wos[1]=s0.y; wos[2]=s0.z; wos[3]=s0.w;
        wos[4]=s1.x; wos[5]=s1.y; wos[6]=s1.z; wos[7]=s1.w;
        won[0]=n0.x; won[1]=n0.y; won[2]=n0.z; won[3]=n0.w;
        won[4]=n1.x; won[5]=n1.y; won[6]=n1.z; won[7]=n1.w;
    }

    const char* wb = (const char*)Wq;
    const unsigned colb = (unsigned)(c * 64 + cg * 8);  // byte offset in 512B row

    #pragma unroll
    for (int it = 0; it < 4; ++it) {
        const int lrow  = wid * 8 + 2 * it + r;
        const int row_g = row_base + lrow;

        const int*   po = &s_off[lrow][fg];
        const float* ps = &s_vs[lrow][fg];
        const float* pn = &s_vn[lrow][fg];

        const int o0 = po[0],  o1 = po[4],  o2 = po[8],  o3 = po[12];
        const int o4 = po[16], o5 = po[20], o6 = po[24], o7 = po[28];
        const int q0 = po[32], q1 = po[36], q2 = po[40], q3 = po[44];
        const int q4 = po[48], q5 = po[52], q6 = po[56], q7 = po[60];
        const float vs0 = ps[0],  vs1 = ps[4],  vs2 = ps[8],  vs3 = ps[12];
        const float vs4 = ps[16], vs5 = ps[20], vs6 = ps[24], vs7 = ps[28];
        const float vn0 = pn[0],  vn1 = pn[4],  vn2 = pn[8],  vn3 = pn[12];
        const float vn4 = pn[16], vn5 = pn[20], vn6 = pn[24], vn7 = pn[28];

        // stm gathers (8 x 512B instr)
        const uint2 a0 = *(const uint2*)(wb + (unsigned)o0 + colb);
        const uint2 a1 = *(const uint2*)(wb + (unsigned)o1 + colb);
        const uint2 a2 = *(const uint2*)(wb + (unsigned)o2 + colb);
        const uint2 a3 = *(const uint2*)(wb + (unsigned)o3 + colb);
        const uint2 a4 = *(const uint2*)(wb + (unsigned)o4 + colb);
        const uint2 a5 = *(const uint2*)(wb + (unsigned)o5 + colb);
        const uint2 a6 = *(const uint2*)(wb + (unsigned)o6 + colb);
        const uint2 a7 = *(const uint2*)(wb + (unsigned)o7 + colb);
        // nstm gathers
        const uint2 b0 = *(const uint2*)(wb + (unsigned)q0 + colb);
        const uint2 b1 = *(const uint2*)(wb + (unsigned)q1 + colb);
        const uint2 b2 = *(const uint2*)(wb + (unsigned)q2 + colb);
        const uint2 b3 = *(const uint2*)(wb + (unsigned)q3 + colb);
        const uint2 b4 = *(const uint2*)(wb + (unsigned)q4 + colb);
        const uint2 b5 = *(const uint2*)(wb + (unsigned)q5 + colb);
        const uint2 b6 = *(const uint2*)(wb + (unsigned)q6 + colb);
        const uint2 b7 = *(const uint2*)(wb + (unsigned)q7 + colb);
        __builtin_amdgcn_sched_barrier(0);   // keep 16 gathers in flight

        // bias-fold: acc = bias/4 - 128*sum(v*scale)
        const float corr_s = 128.f * (((vs0+vs1)+(vs2+vs3)) + ((vs4+vs5)+(vs6+vs7)));
        const float corr_n = 128.f * (((vn0+vn1)+(vn2+vn3)) + ((vn4+vn5)+(vn6+vn7)));

        float acc_s[8], acc_n[8];
        #pragma unroll
        for (int t = 0; t < 8; ++t) {
            acc_s[t] = bbq[t] - corr_s;
            acc_n[t] = bbq[t] - corr_n;
        }

        CONS_U8(acc_s, a0, vs0); CONS_U8(acc_s, a1, vs1);
        CONS_U8(acc_s, a2, vs2); CONS_U8(acc_s, a3, vs3);
        CONS_U8(acc_s, a4, vs4); CONS_U8(acc_s, a5, vs5);
        CONS_U8(acc_s, a6, vs6); CONS_U8(acc_s, a7, vs7);
        CONS_U8(acc_n, b0, vn0); CONS_U8(acc_n, b1, vn1);
        CONS_U8(acc_n, b2, vn2); CONS_U8(acc_n, b3, vn3);
        CONS_U8(acc_n, b4, vn4); CONS_U8(acc_n, b5, vn5);
        CONS_U8(acc_n, b6, vn6); CONS_U8(acc_n, b7, vn7);

        // fg-butterfly: 2 stages (lane bits 3,4)
        #pragma unroll
        for (int t = 0; t < 8; ++t) {
            acc_s[t] += __shfl_xor(acc_s[t], 8);
            acc_n[t] += __shfl_xor(acc_n[t], 8);
        }
        #pragma unroll
        for (int t = 0; t < 8; ++t) {
            acc_s[t] += __shfl_xor(acc_s[t], 16);
            acc_n[t] += __shfl_xor(acc_n[t], 16);
        }

        // clip + dot
        float part = 0.f;
        #pragma unroll
        for (int t = 0; t < 8; ++t) {
            const float hs = fminf(fmaxf(acc_s[t], 0.f), 1.f);
            part = fmaf(hs, wos[t], part);
        }
        #pragma unroll
        for (int t = 0; t < 8; ++t) {
            const float hn = fminf(fmaxf(acc_n[t], 0.f), 1.f);
            part = fmaf(hn, won[t], part);
        }
        part += __shfl_xor(part, 1);
        part += __shfl_xor(part, 2);
        part += __shfl_xor(part, 4);

        if ((lane & 31) == 0 && row_g < batch)
            partial[row_g * NCHUNK + c] = part;
    }
}

// ---------------------------------------------------------------------------
// Kernel 3: combine 8 chunk partials -> sigmoid
// ---------------------------------------------------------------------------
__global__ __launch_bounds__(256)
void final_out(const float* __restrict__ partial,
               const float* __restrict__ b_out,
               float* __restrict__ out, int batch)
{
    const int b = blockIdx.x * 256 + threadIdx.x;
    if (b >= batch) return;
    const float4 p0 = *(const float4*)(partial + b * NCHUNK);
    const float4 p1 = *(const float4*)(partial + b * NCHUNK + 4);
    const float tot = ((p0.x + p0.y) + (p0.z + p0.w))
                    + ((p1.x + p1.y) + (p1.z + p1.w)) + b_out[0];
    out[b] = 1.0f / (1.0f + expf(-tot));
}

// ---------------------------------------------------------------------------
// Fallback: no workspace needed (round-1 kernel).
// ---------------------------------------------------------------------------
__global__ __launch_bounds__(256)
void nnhalfka_fused(const int* __restrict__ stm_idx,
                    const int* __restrict__ nstm_idx,
                    const float* __restrict__ values,
                    const float* __restrict__ W_ft,
                    const float* __restrict__ b_ft,
                    const float* __restrict__ W_fft,
                    const float* __restrict__ b_fft,
                    const float* __restrict__ W_out,
                    const float* __restrict__ b_out,
                    float* __restrict__ out,
                    int nnz)
{
    const int b   = blockIdx.x;
    const int tid = threadIdx.x;

    __shared__ int   s_fs[MAXF], s_fsm[MAXF], s_fn[MAXF], s_fnm[MAXF];
    __shared__ float s_v[MAXF];
    __shared__ float s_red[4];

    if (tid < MAXF) {
        const int g  = b * MAXF + tid;
        const int fs = stm_idx[nnz + g];
        const int fn = nstm_idx[nnz + g];
        s_fs[tid]  = fs * FTOUT;
        s_fsm[tid] = (fs % VFT) * FTOUT;
        s_fn[tid]  = fn * FTOUT;
        s_fnm[tid] = (fn % VFT) * FTOUT;
        s_v[tid]   = values[g];
    }
    __syncthreads();

    const int j = tid * 2;
    float2 accs = make_float2(0.f, 0.f);
    float2 accn = make_float2(0.f, 0.f);

    #pragma unroll 4
    for (int k = 0; k < MAXF; ++k) {
        const float v    = s_v[k];
        const float2 ws  = *(const float2*)(W_ft  + s_fs[k]  + j);
        const float2 wfs = *(const float2*)(W_fft + s_fsm[k] + j);
        const float2 wn  = *(const float2*)(W_ft  + s_fn[k]  + j);
        const float2 wfn = *(const float2*)(W_fft + s_fnm[k] + j);
        accs.x += v * (ws.x + wfs.x);
        accs.y += v * (ws.y + wfs.y);
        accn.x += v * (wn.x + wfn.x);
        accn.y += v * (wn.y + wfn.y);
    }

    const float bb0 = b_ft[j]     + b_fft[j];
    const float bb1 = b_ft[j + 1] + b_fft[j + 1];
    const float hs0 = fminf(fmaxf(accs.x + bb0, 0.f), 1.f);
    const float hs1 = fminf(fmaxf(accs.y + bb1, 0.f), 1.f);
    const float hn0 = fminf(fmaxf(accn.x + bb0, 0.f), 1.f);
    const float hn1 = fminf(fmaxf(accn.y + bb1, 0.f), 1.f);

    float partial = hs0 * W_out[j]         + hs1 * W_out[j + 1]
                  + hn0 * W_out[FTOUT + j] + hn1 * W_out[FTOUT + j + 1];
    #pragma unroll
    for (int off = 32; off > 0; off >>= 1)
        partial += __shfl_down(partial, off);
    if ((tid & 63) == 0) s_red[tid >> 6] = partial;
    __syncthreads();
    if (tid == 0) {
        const float tot = s_red[0] + s_red[1] + s_red[2] + s_red[3] + b_out[0];
        out[b] = 1.0f / (1.0f + expf(-tot));
    }
}

extern "C" void kernel_launch(void* const* d_in, const int* in_sizes, int n_in,
                              void* d_out, int out_size, void* d_ws, size_t ws_size,
                              hipStream_t stream) {
    const int*   stm_idx  = (const int*)d_in[0];
    const int*   nstm_idx = (const int*)d_in[1];
    const float* values   = (const float*)d_in[2];
    const float* W_ft     = (const float*)d_in[4];
    const float* b_ft     = (const float*)d_in[5];
    const float* W_fft    = (const float*)d_in[6];
    const float* b_fft    = (const float*)d_in[7];
    const float* W_out    = (const float*)d_in[8];
    const float* b_out    = (const float*)d_in[9];
    float* out = (float*)d_out;

    const int nnz   = in_sizes[0] / 2;
    const int batch = out_size;

    const size_t WQ_B   = (size_t)FTIN * FTOUT;          // 25,165,824
    const size_t SC_B   = (size_t)FTIN * 4;              // 196,608
    const size_t OFF_B  = (size_t)batch * 64 * 2;
    const size_t VS_B   = (size_t)batch * 32 * 4;
    const size_t VN_B   = (size_t)batch * 32 * 4;
    const size_t PART_B = (size_t)batch * NCHUNK * 4;
    const size_t need = WQ_B + SC_B + OFF_B + VS_B + VN_B + PART_B;

    if (ws_size >= need && (batch % RPB) == 0) {
        char* p = (char*)d_ws;
        unsigned char*  Wq      = (unsigned char*)p;        p += WQ_B;
        float*          scale   = (float*)p;                p += SC_B;
        unsigned short* off16   = (unsigned short*)p;       p += OFF_B;
        float*          val_s   = (float*)p;                p += VS_B;
        float*          val_n   = (float*)p;                p += VN_B;
        float*          partial = (float*)p;

        build_q8<<<FTIN / 4, 256, 0, stream>>>(W_ft, W_fft, Wq, scale);
        prep_idx<<<(batch * 64 + 255) / 256, 256, 0, stream>>>(
            stm_idx, nstm_idx, values, scale, off16, val_s, val_n, nnz, batch);
        gather_q8<<<(batch / RPB) * NCHUNK, 256, 0, stream>>>(
            Wq, off16, val_s, val_n, b_ft, b_fft, W_out, partial, batch);
        final_out<<<(batch + 255) / 256, 256, 0, stream>>>(partial, b_out, out, batch);
    } else {
        nnhalfka_fused<<<batch, 256, 0, stream>>>(
            stm_idx, nstm_idx, values, W_ft, b_ft, W_fft, b_fft, W_out, b_out,
            out, nnz);
    }
}